// Round 2
// baseline (2597.963 us; speedup 1.0000x reference)
//
#include <hip/hip_runtime.h>
#include <hip/hip_bf16.h>

// ClippedGRU: B=256, T=500, I=128, H=512, clip ±5. fp32 in/out, bf16 MFMA core.
//
// Persistent cooperative kernel. Grid = 256 blocks = 16 batch-groups (16 rows
// = MFMA M) x 16 unit-strips (32 h-units -> 96 rows of W_hh/W_ih). W strips
// live in registers as MFMA B-fragments (6 GEMM waves).
//
// Sync scheme (this revision): the h exchange buffer carries its own readiness
// tag -- each published unit is a u32 word (step_tag<<16 | bf16 h). Publishers
// fire relaxed agent-scope 8B stores (coherent at the IF point, no fence, no
// ack wait, no separate flag). Consumers poll exactly the words they need
// until all tags equal the current step. This reduces the per-step critical
// path to ONE far-visibility latency + poll cadence (previous scheme had three
// serialized IF round trips: h-store ack inside __syncthreads, flag trip,
// h load). Barriers are raw s_barrier with writer-side lgkmcnt(0) only, so no
// barrier waits on global-store acks (out/publish stores drain off-path; vmcnt
// in-order retirement orders same-address publishes 2 steps apart).
//
// Slot reuse safety (2-slot buffer, 1-step lag): publishing h_{t+1} is
// data-dependent on having staged h_t, which required all peers to publish
// h_t, which is data-dependent on their h_{t-1} staging loads having been
// serviced -- so overwriting slot (t+1)&1 = (t-1)&1 is safe.

#define T_STEPS 500
#define B_TOT   256
#define I_DIM   128
#define H_DIM   512
#define BB      16      // batch rows per group (= MFMA M)
#define UU      32      // h-units per block strip

typedef __bf16 bf16x8 __attribute__((ext_vector_type(8)));
typedef float  f32x4  __attribute__((ext_vector_type(4)));
typedef float  f32x8  __attribute__((ext_vector_type(8)));
typedef unsigned short u16;
typedef unsigned int   u32;
typedef unsigned long long u64;

__device__ __forceinline__ bf16x8 cvt8(const float* p) {
    f32x8 v = *(const f32x8*)p;   // 32B load (2x dwordx4)
    bf16x8 r;
#pragma unroll
    for (int i = 0; i < 8; ++i) r[i] = (__bf16)v[i];   // RNE cvt
    return r;
}

__device__ __forceinline__ float fast_sigmoid(float x) {
    float e = __builtin_amdgcn_exp2f(-1.4426950408889634f * x);
    return __builtin_amdgcn_rcpf(1.0f + e);
}
__device__ __forceinline__ float fast_tanh(float x) {
    float e = __builtin_amdgcn_exp2f(2.8853900817779268f * x);
    return 1.0f - 2.0f * __builtin_amdgcn_rcpf(1.0f + e);
}

// raw barrier, writer-side LDS drain only (no vmcnt drain)
#define BAR_LDS()                                              \
    do {                                                       \
        asm volatile("s_waitcnt lgkmcnt(0)" ::: "memory");     \
        __builtin_amdgcn_sched_barrier(0);                     \
        __builtin_amdgcn_s_barrier();                          \
        __builtin_amdgcn_sched_barrier(0);                     \
    } while (0)
#define BAR_RAW()                                              \
    do {                                                       \
        __builtin_amdgcn_sched_barrier(0);                     \
        __builtin_amdgcn_s_barrier();                          \
        __builtin_amdgcn_sched_barrier(0);                     \
    } while (0)

__global__ __launch_bounds__(512, 2)
void gru_persist(const float* __restrict__ x,
                 const float* __restrict__ h0,
                 const float* __restrict__ wih,
                 const float* __restrict__ whh,
                 const float* __restrict__ bih,
                 const float* __restrict__ bhh,
                 float* __restrict__ out,
                 u32* __restrict__ hbuf)   // [2][256][512] (tag<<16 | bf16)
{
    const int tid  = threadIdx.x;
    const int bx   = blockIdx.x;
    const int g    = bx >> 4;          // batch group 0..15
    const int j    = bx & 15;          // unit strip 0..15
    const int bg   = g * BB;           // batch base
    const int u0   = j * UU;           // unit base
    const int w    = tid >> 6;         // wave 0..7 (0-5 GEMM)
    const int lane = tid & 63;
    const int lrow = lane & 15;        // MFMA m / n index within fragment
    const int lq   = lane >> 4;        // quad 0..3

    __shared__ float s_g[4][16 * 36];  // r, z, hh_n, xi_n (stride 36, 16B-align)
    __shared__ float s_hold[16 * 32];  // fp32 carried h strip (never rounded)
    __shared__ float s_bih[96];
    __shared__ float s_bhh[96];
    __shared__ __hip_bfloat16 s_h[16 * 512];  // staged h tile, XOR-swizzled

    // ---- one-time init ----
    {
        int b = tid >> 5, u = tid & 31;
        s_hold[b * 32 + u] = h0[(size_t)(bg + b) * H_DIM + u0 + u];
        if (tid < 96) {
            int gg = tid >> 5, uu = tid & 31;
            s_bih[tid] = bih[gg * H_DIM + u0 + uu];
            s_bhh[tid] = bhh[gg * H_DIM + u0 + uu];
        }
    }

    // ---- one-time: W_hh / W_ih strips -> bf16 register B-fragments ----
    const int gate = w >> 1;
    const int hf   = w & 1;
    bf16x8 wf[16], wfi[4];
    if (w < 6) {
        const long row0 = (long)gate * H_DIM + u0 + 16 * hf;  // row in [0,1536)
        const float* wr  = whh + (row0 + lrow) * H_DIM + lq * 8;
        const float* wr2 = wih + (row0 + lrow) * I_DIM + lq * 8;
#pragma unroll
        for (int kt = 0; kt < 16; ++kt) wf[kt] = cvt8(wr + kt * 32);
#pragma unroll
        for (int kt = 0; kt < 4; ++kt)  wfi[kt] = cvt8(wr2 + kt * 32);
    }
    __syncthreads();

    // staging: row sr (0..15), chunk sc (0..31) -> units sc*16 .. sc*16+15.
    // LDS dest byte offset XORed with (sr&7)<<4 (bank-conflict-free frag reads).
    const int sr = tid >> 5, sc = tid & 31;
    char* sd0 = (char*)s_h + sr * 1024 + ((sc * 32     ) ^ ((sr & 7) << 4));
    char* sd1 = (char*)s_h + sr * 1024 + ((sc * 32 + 16) ^ ((sr & 7) << 4));
    // tagged-source pointers (both slots) for this thread's 16 units
    const u64* hp0 = (const u64*)(hbuf + (size_t)(bg + sr) * H_DIM + sc * 16);
    const u64* hp1 = (const u64*)((const u32*)hp0 + (size_t)B_TOT * H_DIM);

    int sync_ok = 1;  // timeout latch (fail-fast, no hang)

#pragma unroll 1
    for (int t = 0; t < T_STEPS; ++t) {
        f32x4 accA = {0, 0, 0, 0}, accB = {0, 0, 0, 0}, accX = {0, 0, 0, 0};

        // ---- A: x fragment loads for step t (plain cached loads) ----
        bf16x8 xf0, xf1, xf2, xf3;
        if (w < 6) {
            const float* xr =
                x + ((size_t)(bg + lrow) * T_STEPS + t) * I_DIM + lq * 8;
            xf0 = cvt8(xr);
            xf1 = cvt8(xr + 32);
            xf2 = cvt8(xr + 64);
            xf3 = cvt8(xr + 96);
        }

        // ---- B0: issue first tagged-h load round (flies under ih MFMAs) ----
        const u64* hp = (t & 1) ? hp1 : hp0;
        u64 q[8];
        if (t > 0) {
#pragma unroll
            for (int i = 0; i < 8; ++i)
                q[i] = __hip_atomic_load(hp + i, __ATOMIC_RELAXED,
                                         __HIP_MEMORY_SCOPE_AGENT);
        }

        // ---- A2: ih GEMM MFMAs ----
        if (w < 6) {
            f32x4 ai = {0, 0, 0, 0};
            ai = __builtin_amdgcn_mfma_f32_16x16x32_bf16(xf0, wfi[0], ai, 0, 0, 0);
            ai = __builtin_amdgcn_mfma_f32_16x16x32_bf16(xf1, wfi[1], ai, 0, 0, 0);
            ai = __builtin_amdgcn_mfma_f32_16x16x32_bf16(xf2, wfi[2], ai, 0, 0, 0);
            ai = __builtin_amdgcn_mfma_f32_16x16x32_bf16(xf3, wfi[3], ai, 0, 0, 0);
            if (gate < 2) accA = ai; else accX = ai;
        }

        // ---- B1: poll tags == t, then extract bf16 ----
        bf16x8 sv0, sv1;
        if (t == 0) {
            const float* hps = h0 + (size_t)(bg + sr) * H_DIM + sc * 16;
            sv0 = cvt8(hps);
            sv1 = cvt8(hps + 8);
        } else {
            const u64 expect = ((u64)(u32)t << 16) | ((u64)(u32)t << 48);
            const u64 mask   = 0xFFFF0000FFFF0000ull;
            long tries = 0;
            while (sync_ok) {
                u64 m = 0;
#pragma unroll
                for (int i = 0; i < 8; ++i) m |= (q[i] & mask) ^ expect;
                if (m == 0) break;
                __builtin_amdgcn_s_sleep(1);
                if (++tries > (1L << 20)) { sync_ok = 0; break; }
#pragma unroll
                for (int i = 0; i < 8; ++i)
                    q[i] = __hip_atomic_load(hp + i, __ATOMIC_RELAXED,
                                             __HIP_MEMORY_SCOPE_AGENT);
            }
            union { u16 s[8]; bf16x8 v; } ua, ub;
#pragma unroll
            for (int i = 0; i < 4; ++i) {
                ua.s[2 * i]     = (u16)q[i];
                ua.s[2 * i + 1] = (u16)(q[i] >> 32);
                ub.s[2 * i]     = (u16)q[4 + i];
                ub.s[2 * i + 1] = (u16)(q[4 + i] >> 32);
            }
            sv0 = ua.v;
            sv1 = ub.v;
        }

        // ---- C: write staged tile to LDS ----
        *(bf16x8*)sd0 = sv0;
        *(bf16x8*)sd1 = sv1;
        BAR_LDS();                                     // D

        // ---- E: hh GEMM: A = LDS h fragments, B = register W ----
        if (w < 6) {
            const char* ab  = (const char*)s_h + lrow * 1024;
            const int   swz = (lrow & 7) << 4;
#pragma unroll
            for (int kt = 0; kt < 8; ++kt) {
                bf16x8 hfr = *(const bf16x8*)(ab + ((lq * 16 + kt * 64) ^ swz));
                accA = __builtin_amdgcn_mfma_f32_16x16x32_bf16(hfr, wf[kt],
                                                               accA, 0, 0, 0);
            }
#pragma unroll
            for (int kt = 8; kt < 16; ++kt) {
                bf16x8 hfr = *(const bf16x8*)(ab + ((lq * 16 + kt * 64) ^ swz));
                accB = __builtin_amdgcn_mfma_f32_16x16x32_bf16(hfr, wf[kt],
                                                               accB, 0, 0, 0);
            }
            // C layout: col = lane&15 (unit), row = (lane>>4)*4+i (batch)
            const int col = hf * 16 + lrow;
#pragma unroll
            for (int i = 0; i < 4; ++i) {
                int b = lq * 4 + i;
                s_g[gate][b * 36 + col] = accA[i] + accB[i];
                if (gate == 2) s_g[3][b * 36 + col] = accX[i];
            }
        }
        BAR_LDS();                                     // F

        // ---- G: gate math, 128 threads x 4 units, tagged 8B publishes ----
        if (tid < 128) {
            const int b  = tid >> 3;
            const int ub = (tid & 7) * 4;
            f32x4 vr  = *(const f32x4*)&s_g[0][b * 36 + ub];
            f32x4 vz  = *(const f32x4*)&s_g[1][b * 36 + ub];
            f32x4 vhn = *(const f32x4*)&s_g[2][b * 36 + ub];
            f32x4 vxn = *(const f32x4*)&s_g[3][b * 36 + ub];
            f32x4 hold = *(const f32x4*)&s_hold[b * 32 + ub];
            f32x4 hnew;
            u32 wd[4];
            const u32 tagw = (u32)(t + 1) << 16;
#pragma unroll
            for (int i = 0; i < 4; ++i) {
                float rr = fast_sigmoid(vr[i] + s_bih[ub + i] + s_bhh[ub + i]);
                float zz = fast_sigmoid(vz[i] + s_bih[32 + ub + i] +
                                        s_bhh[32 + ub + i]);
                float nn = fast_tanh(vxn[i] + s_bih[64 + ub + i] +
                                     rr * (vhn[i] + s_bhh[64 + ub + i]));
                float hv = (1.0f - zz) * nn + zz * hold[i];
                hv = fminf(fmaxf(hv, -5.0f), 5.0f);
                hnew[i] = hv;
                __bf16 hb = (__bf16)hv;
                wd[i] = tagw | (u32)__builtin_bit_cast(u16, hb);
            }
            // publish FIRST (fire-and-forget, visibility = the tag itself)
            if (t < T_STEPS - 1) {
                u64* dst = (u64*)(hbuf + (size_t)((t + 1) & 1) * B_TOT * H_DIM +
                                  (size_t)(bg + b) * H_DIM + u0 + ub);
                __hip_atomic_store(dst, (u64)wd[0] | ((u64)wd[1] << 32),
                                   __ATOMIC_RELAXED, __HIP_MEMORY_SCOPE_AGENT);
                __hip_atomic_store(dst + 1, (u64)wd[2] | ((u64)wd[3] << 32),
                                   __ATOMIC_RELAXED, __HIP_MEMORY_SCOPE_AGENT);
            }
            *(f32x4*)&s_hold[b * 32 + ub] = hnew;
            *(f32x4*)(out + ((size_t)(bg + b) * T_STEPS + t) * H_DIM + u0 + ub)
                = hnew;
            if (t == T_STEPS - 1)
                *(f32x4*)(out + (size_t)B_TOT * T_STEPS * H_DIM +
                          (size_t)(bg + b) * H_DIM + u0 + ub) = hnew;
        }
        BAR_RAW();   // H: no drains; s_g/s_h reuse hazards covered by D/F
    }
}

extern "C" void kernel_launch(void* const* d_in, const int* in_sizes, int n_in,
                              void* d_out, int out_size, void* d_ws, size_t ws_size,
                              hipStream_t stream) {
    const float* x   = (const float*)d_in[0];
    const float* h0  = (const float*)d_in[1];
    const float* wih = (const float*)d_in[2];
    const float* whh = (const float*)d_in[3];
    const float* bih = (const float*)d_in[4];
    const float* bhh = (const float*)d_in[5];
    float* out = (float*)d_out;
    u32* hbuf = (u32*)d_ws;   // 2*256*512*4B = 1 MB tagged h exchange

    // No memset needed: ws is re-poisoned to 0xAA -> tag field 0xAAAA never
    // matches any expected step tag (1..499).

    void* args[] = { (void*)&x, (void*)&h0, (void*)&wih, (void*)&whh,
                     (void*)&bih, (void*)&bhh, (void*)&out, (void*)&hbuf };
    // Cooperative launch guarantees all 256 blocks (1/CU) are co-resident,
    // which the group-local tag-poll barriers require.
    hipLaunchCooperativeKernel((void*)gru_persist, dim3(256), dim3(512),
                               args, 0, stream);
}